// Round 3
// baseline (203.388 us; speedup 1.0000x reference)
//
#include <hip/hip_runtime.h>
#include <hip/hip_bf16.h>
#include <math.h>

constexpr int BB = 2;
constexpr int LL = 1024;
constexpr int DD = 768;
constexpr int HH = 12;
constexpr int NEz = 42;
constexpr int MM = 8;
constexpr int NPp = 1722;
constexpr int CC = 97;
constexpr int FF = 256;
constexpr int PAIRS = NEz * NEz;         // 1764
constexpr int TOTAL = BB * NPp;          // 3444
constexpr int PT64 = (TOTAL + 63) / 64;  // 54
constexpr int OG = 8;
constexpr int OGRP = (CC + OG - 1) / OG; // 13
constexpr int NWG = PT64 * OGRP;         // 702

typedef float f32x4 __attribute__((ext_vector_type(4)));
typedef short bf16x8 __attribute__((ext_vector_type(8)));

__device__ inline short f2bs(float x) {
    __hip_bfloat16 b = __float2bfloat16(x);
    return *(short*)&b;
}

// ---------------- K1: seqW[b,l,k] = sum_d seq[b,l,d] * W_lin[d,k] ----------------
__global__ void k_seqw(const float* __restrict__ seq, const float* __restrict__ Wl,
                       float* __restrict__ seqW) {
    int bl = blockIdx.x;
    int lane = threadIdx.x;
    const float* row = seq + (size_t)bl * DD;
    float a0 = 0.f, a1 = 0.f, a2 = 0.f;
    for (int d = lane; d < DD; d += 64) {
        float v = row[d];
        a0 += v * Wl[d * 3 + 0];
        a1 += v * Wl[d * 3 + 1];
        a2 += v * Wl[d * 3 + 2];
    }
    for (int off = 32; off; off >>= 1) {
        a0 += __shfl_down(a0, off);
        a1 += __shfl_down(a1, off);
        a2 += __shfl_down(a2, off);
    }
    if (lane == 0) {
        seqW[bl * 3 + 0] = a0;
        seqW[bl * 3 + 1] = a1;
        seqW[bl * 3 + 2] = a2;
    }
}

// ---------------- K2: ent_emb = masked logsumexp over M mentions ----------------
__global__ void k_ent_emb(const float* __restrict__ seq, const int* __restrict__ midx,
                          const int* __restrict__ mmask, float* __restrict__ ent_emb) {
    int be = blockIdx.x;
    int b = be / NEz;
    int tid = threadIdx.x;
    int idx[MM], msk[MM];
#pragma unroll
    for (int m = 0; m < MM; ++m) {
        idx[m] = midx[be * MM + m];
        msk[m] = mmask[be * MM + m];
    }
    const float* sb = seq + (size_t)b * LL * DD;
    for (int d = tid; d < DD; d += 256) {
        float v[MM];
        float mx = -1e30f;
#pragma unroll
        for (int m = 0; m < MM; ++m) {
            v[m] = msk[m] ? sb[(size_t)idx[m] * DD + d] : -1e30f;
            mx = fmaxf(mx, v[m]);
        }
        float s = 0.f;
#pragma unroll
        for (int m = 0; m < MM; ++m) s += expf(v[m] - mx);
        ent_emb[(size_t)be * DD + d] = mx + logf(s);
    }
}

// ---------------- K3: ent_att ----------------
__global__ void k_ent_att(const float* __restrict__ att, const int* __restrict__ midx,
                          const int* __restrict__ mmask, float* __restrict__ ea) {
    int beh = blockIdx.x;
    int h = beh % HH;
    int be = beh / HH;
    int b = be / NEz;
    int tid = threadIdx.x;
    int idx[MM], msk[MM];
    float msum = 0.f;
#pragma unroll
    for (int m = 0; m < MM; ++m) {
        idx[m] = midx[be * MM + m];
        msk[m] = mmask[be * MM + m];
        msum += (float)msk[m];
    }
    float inv = 1.f / msum;
    const float* ab = att + ((size_t)b * HH + h) * LL * LL;
#pragma unroll
    for (int li = 0; li < 4; ++li) {
        int l = tid + li * 256;
        float acc = 0.f;
#pragma unroll
        for (int m = 0; m < MM; ++m)
            if (msk[m]) acc += ab[(size_t)idx[m] * LL + l];
        ea[(size_t)beh * LL + l] = acc * inv;
    }
}

// ---------------- K4: per pair: ht_att -> normalize -> z -> attn_map row ---------
__global__ void k_pair(const float* __restrict__ ea, const float* __restrict__ seqW,
                       const float* __restrict__ Wseg, const float* __restrict__ bseg,
                       const float* __restrict__ blin, float* __restrict__ am) {
    int bp = blockIdx.x;
    int b = bp / PAIRS;
    int p = bp % PAIRS;
    int e1 = p / NEz, e2 = p % NEz;
    int tid = threadIdx.x;
    int lane = tid & 63, wid = tid >> 6;

    const float* ea1 = ea + ((size_t)(b * NEz + e1)) * HH * LL;
    const float* ea2 = ea + ((size_t)(b * NEz + e2)) * HH * LL;

    float myht[4];
    float lsum = 0.f;
#pragma unroll
    for (int li = 0; li < 4; ++li) {
        int l = tid + li * 256;
        float acc = 0.f;
#pragma unroll
        for (int h = 0; h < HH; ++h) acc += ea1[h * LL + l] * ea2[h * LL + l];
        acc *= (1.0f / HH);
        myht[li] = acc;
        lsum += acc;
    }
    __shared__ float red4[4];
    __shared__ float redz[3][4];
    for (int off = 32; off; off >>= 1) lsum += __shfl_down(lsum, off);
    if (lane == 0) red4[wid] = lsum;
    __syncthreads();
    float s = red4[0] + red4[1] + red4[2] + red4[3];
    float scale = 1.f / (s + 1e-5f);

    float z0 = 0.f, z1 = 0.f, z2 = 0.f;
#pragma unroll
    for (int li = 0; li < 4; ++li) {
        int l = tid + li * 256;
        float w = myht[li] * scale;
        const float* sw = seqW + ((size_t)b * LL + l) * 3;
        z0 += w * sw[0];
        z1 += w * sw[1];
        z2 += w * sw[2];
    }
    for (int off = 32; off; off >>= 1) {
        z0 += __shfl_down(z0, off);
        z1 += __shfl_down(z1, off);
        z2 += __shfl_down(z2, off);
    }
    if (lane == 0) { redz[0][wid] = z0; redz[1][wid] = z1; redz[2][wid] = z2; }
    __syncthreads();
    float ai0 = redz[0][0] + redz[0][1] + redz[0][2] + redz[0][3] + blin[0];
    float ai1 = redz[1][0] + redz[1][1] + redz[1][2] + redz[1][3] + blin[1];
    float ai2 = redz[2][0] + redz[2][1] + redz[2][2] + redz[2][3] + blin[2];
    float val = ai0 * Wseg[0 * FF + tid] + ai1 * Wseg[1 * FF + tid] +
                ai2 * Wseg[2 * FF + tid] + bseg[tid];
    am[(size_t)bp * FF + tid] = fmaxf(val, 0.f);
}

// ---------------- K5: EWh/EWt = ent_emb @ W_head/tail + bias ---------------------
__global__ void k_ew(const float* __restrict__ ent_emb, const float* __restrict__ Wh,
                     const float* __restrict__ bh, const float* __restrict__ Wt,
                     const float* __restrict__ bt, float* __restrict__ EWh,
                     float* __restrict__ EWt) {
    int be = blockIdx.x;
    int tid = threadIdx.x;
    __shared__ float e[DD];
    for (int d = tid; d < DD; d += 256) e[d] = ent_emb[(size_t)be * DD + d];
    __syncthreads();
    float ah = bh[tid], at = bt[tid];
    for (int d = 0; d < DD; ++d) {
        float ev = e[d];
        ah += ev * Wh[d * FF + tid];
        at += ev * Wt[d * FF + tid];
    }
    EWh[(size_t)be * FF + tid] = ah;
    EWt[(size_t)be * FF + tid] = at;
}

// ---------------- K6a: Wt_swz = pre-swizzled LDS chunk images of W_bil^T ---------
// Chunk kc image (32 KB): byte (n*128 + k16*16) ^ ((n&7)<<4) holds bf16x8 of
// W[o][kc*64 + k16*8 .. +8][n].
__global__ void k_wt(const float* __restrict__ Wb, __hip_bfloat16* __restrict__ Wt) {
    int o = blockIdx.y;
    int ti = blockIdx.x >> 2;   // k-chunk kc
    int tj = blockIdx.x & 3;    // n tile
    int tid = threadIdx.x;      // 256
    int lane = tid & 63, quad = tid >> 6;
    __shared__ float t64[64][65];
    const float* src = Wb + (size_t)o * FF * FF;
#pragma unroll 4
    for (int i = 0; i < 16; ++i) {
        int kr = quad * 16 + i;
        t64[kr][lane] = src[(size_t)(ti * 64 + kr) * FF + tj * 64 + lane];
    }
    __syncthreads();
    char* dst = (char*)Wt + (size_t)o * 131072 + (size_t)ti * 32768;
#pragma unroll
    for (int u2 = 0; u2 < 2; ++u2) {
        int u = tid + u2 * 256;   // 0..511
        int jr = u >> 3;          // 0..63
        int k16 = u & 7;
        int n = tj * 64 + jr;
        bf16x8 val;
#pragma unroll
        for (int kk = 0; kk < 8; ++kk) val[kk] = f2bs(t64[k16 * 8 + kk][jr]);
        *(bf16x8*)(dst + ((n * 128 + k16 * 16) ^ ((n & 7) << 4))) = val;
    }
}

// ---------------- K6b: HS_swz (pre-swizzled A-tile images) + TSb (linear) --------
__global__ void k_prep(const float* __restrict__ EWh, const float* __restrict__ EWt,
                       const float* __restrict__ am, const int* __restrict__ hts,
                       __hip_bfloat16* __restrict__ HS_swz, __hip_bfloat16* __restrict__ TSb) {
    int tile = blockIdx.x;
    int tid = threadIdx.x;   // 256
    char* dstA = (char*)HS_swz + (size_t)tile * 32768;
#pragma unroll
    for (int u2 = 0; u2 < 8; ++u2) {
        int u = tid + u2 * 256;   // 0..2047
        int r = u >> 5;
        int k16 = u & 31;
        int p = tile * 64 + r;
        bf16x8 hv8 = {0, 0, 0, 0, 0, 0, 0, 0};
        bf16x8 tv8 = {0, 0, 0, 0, 0, 0, 0, 0};
        if (p < TOTAL) {
            int b = p / NPp;
            int e1 = hts[p * 2 + 0];
            int e2 = hts[p * 2 + 1];
            const float* amr = am + ((size_t)b * PAIRS + e1 * NEz + e2) * FF + k16 * 8;
            const float* hr = EWh + (size_t)(b * NEz + e1) * FF + k16 * 8;
            const float* tr = EWt + (size_t)(b * NEz + e2) * FF + k16 * 8;
#pragma unroll
            for (int kk = 0; kk < 8; ++kk) {
                float a = amr[kk];
                hv8[kk] = f2bs(tanhf(hr[kk] + a));
                tv8[kk] = f2bs(tanhf(tr[kk] + a));
            }
            *(bf16x8*)((char*)TSb + (size_t)p * 512 + k16 * 16) = tv8;
        }
        *(bf16x8*)(dstA + ((r * 512 + k16 * 16) ^ ((r & 7) << 4))) = hv8;
    }
}

// ---------------- K6c: logits via pipelined MFMA ---------------------------------
#define SYNC_PROD() do { __builtin_amdgcn_sched_barrier(0); \
    asm volatile("s_waitcnt lgkmcnt(0)" ::: "memory"); \
    __builtin_amdgcn_sched_barrier(0); \
    __builtin_amdgcn_s_barrier(); \
    __builtin_amdgcn_sched_barrier(0); } while (0)
#define SYNC_X() do { __builtin_amdgcn_sched_barrier(0); \
    __builtin_amdgcn_s_barrier(); \
    __builtin_amdgcn_sched_barrier(0); } while (0)

__launch_bounds__(512, 4)
__global__ void k_bil_mfma(const __hip_bfloat16* __restrict__ HS_swz,
                           const __hip_bfloat16* __restrict__ TSb,
                           const __hip_bfloat16* __restrict__ Wt_swz,
                           const float* __restrict__ bbil,
                           float* __restrict__ out) {
    // bijective XCD-chunked remap, o-group-major within each XCD
    int f = blockIdx.x;
    constexpr int Q = NWG / 8, R8 = NWG % 8;   // 87, 6
    int xcd = f & 7, sub = f >> 3;
    int wg = (xcd < R8 ? xcd * (Q + 1) : R8 * (Q + 1) + (xcd - R8) * Q) + sub;
    int og = wg / PT64;
    int tile = wg % PT64;
    int p0 = tile * 64;
    int o0 = og * OG;
    int nO = CC - o0 < OG ? CC - o0 : OG;

    int tid = threadIdx.x;
    int lane = tid & 63, w = tid >> 6;
    int wr = w >> 2, wc = w & 3;
    int lr = lane & 15, lg = lane >> 4;

    __shared__ char A_c[32768];
    __shared__ char B_c[32768];
    __shared__ float rowred[64][4];
    __shared__ float outbuf[64][OG];

    bf16x8* Bv = (bf16x8*)B_c;
    const bf16x8* Wu = (const bf16x8*)Wt_swz;

    // ---- stage A: linear copy of pre-swizzled tile ----
    {
        const bf16x8* Asrc = (const bf16x8*)(HS_swz) + (size_t)tile * 2048;
        bf16x8* Av = (bf16x8*)A_c;
#pragma unroll
        for (int it = 0; it < 4; ++it) Av[tid + it * 512] = Asrc[tid + it * 512];
    }

    // ---- TS values held in packed registers (once per block, reused all o) ----
    unsigned tsp[2][4][2];
    {
        const unsigned short* TSu = (const unsigned short*)TSb;
#pragma unroll
        for (int mi = 0; mi < 2; ++mi)
#pragma unroll
            for (int reg = 0; reg < 4; ++reg) {
                int r = wr * 32 + mi * 16 + lg * 4 + reg;
                int p = p0 + r;
#pragma unroll
                for (int np_ = 0; np_ < 2; ++np_) {
                    unsigned lo = 0, hi = 0;
                    if (p < TOTAL) {
                        int c0 = wc * 64 + np_ * 32 + lr;
                        lo = TSu[(size_t)p * FF + c0];
                        hi = TSu[(size_t)p * FF + c0 + 16];
                    }
                    tsp[mi][reg][np_] = lo | (hi << 16);
                }
            }
    }

    // per-thread fragment address bases
    int aoff[2], asw[2], boff[4], bsw[4];
#pragma unroll
    for (int mi = 0; mi < 2; ++mi) {
        int r = wr * 32 + mi * 16 + lr;
        aoff[mi] = r * 512;
        asw[mi] = (r & 7) << 4;
    }
#pragma unroll
    for (int ni = 0; ni < 4; ++ni) {
        int n = wc * 64 + ni * 16 + lr;
        boff[ni] = n * 128;
        bsw[ni] = (n & 7) << 4;
    }

#define PREFETCH(PF, NX) do { \
    const bf16x8* np_ = Wu + ((size_t)(o0 + ((NX) >> 2)) * 8192 + (size_t)((NX) & 3) * 2048); \
    _Pragma("unroll") \
    for (int it_ = 0; it_ < 4; ++it_) PF[it_] = np_[tid + it_ * 512]; \
} while (0)

#define WRITE_B(PF) do { \
    _Pragma("unroll") \
    for (int it_ = 0; it_ < 4; ++it_) Bv[tid + it_ * 512] = PF[it_]; \
} while (0)

#define COMPUTE(KC) do { \
    _Pragma("unroll") \
    for (int ks = 0; ks < 2; ++ks) { \
        bf16x8 af[2], bfr[4]; \
        int k2 = (KC) * 128 + ks * 64 + lg * 16; \
        _Pragma("unroll") \
        for (int mi = 0; mi < 2; ++mi) \
            af[mi] = *(const bf16x8*)(A_c + (aoff[mi] + (k2 ^ asw[mi]))); \
        int kk2 = ks * 64 + lg * 16; \
        _Pragma("unroll") \
        for (int ni = 0; ni < 4; ++ni) \
            bfr[ni] = *(const bf16x8*)(B_c + (boff[ni] + (kk2 ^ bsw[ni]))); \
        __builtin_amdgcn_s_setprio(1); \
        _Pragma("unroll") \
        for (int mi = 0; mi < 2; ++mi) \
            _Pragma("unroll") \
            for (int ni = 0; ni < 4; ++ni) \
                acc[mi][ni] = __builtin_amdgcn_mfma_f32_16x16x32_bf16(af[mi], bfr[ni], acc[mi][ni], 0, 0, 0); \
        __builtin_amdgcn_s_setprio(0); \
    } \
} while (0)

    bf16x8 pfA[4], pfB[4];
    PREFETCH(pfA, 0);

    for (int oi = 0; oi < nO; ++oi) {
        int lastc = nO * 4 - 1;
        int nx1 = oi * 4 + 1; nx1 = nx1 > lastc ? lastc : nx1;
        int nx2 = oi * 4 + 2; nx2 = nx2 > lastc ? lastc : nx2;
        int nx3 = oi * 4 + 3; nx3 = nx3 > lastc ? lastc : nx3;
        int nx4 = oi * 4 + 4; nx4 = nx4 > lastc ? lastc : nx4;

        f32x4 acc[2][4];
#pragma unroll
        for (int mi = 0; mi < 2; ++mi)
#pragma unroll
            for (int ni = 0; ni < 4; ++ni) acc[mi][ni] = (f32x4){0.f, 0.f, 0.f, 0.f};

        PREFETCH(pfB, nx1); SYNC_X(); WRITE_B(pfA); SYNC_PROD(); COMPUTE(0);
        PREFETCH(pfA, nx2); SYNC_X(); WRITE_B(pfB); SYNC_PROD(); COMPUTE(1);
        PREFETCH(pfB, nx3); SYNC_X(); WRITE_B(pfA); SYNC_PROD(); COMPUTE(2);
        PREFETCH(pfA, nx4); SYNC_X(); WRITE_B(pfB); SYNC_PROD(); COMPUTE(3);

        // ---- epilogue: dot with TS (registers), reduce over lanes ----
#pragma unroll
        for (int mi = 0; mi < 2; ++mi)
#pragma unroll
            for (int reg = 0; reg < 4; ++reg) {
                unsigned u0 = tsp[mi][reg][0], u1 = tsp[mi][reg][1];
                float t0 = __uint_as_float((u0 & 0xFFFFu) << 16);
                float t1 = __uint_as_float(u0 & 0xFFFF0000u);
                float t2 = __uint_as_float((u1 & 0xFFFFu) << 16);
                float t3 = __uint_as_float(u1 & 0xFFFF0000u);
                float s = acc[mi][0][reg] * t0 + acc[mi][1][reg] * t1 +
                          acc[mi][2][reg] * t2 + acc[mi][3][reg] * t3;
                s += __shfl_xor(s, 1);
                s += __shfl_xor(s, 2);
                s += __shfl_xor(s, 4);
                s += __shfl_xor(s, 8);
                if (lr == 0) rowred[wr * 32 + mi * 16 + lg * 4 + reg][wc] = s;
            }
        SYNC_PROD();
        if (tid < 64)
            outbuf[tid][oi] = rowred[tid][0] + rowred[tid][1] + rowred[tid][2] + rowred[tid][3];
    }

    SYNC_PROD();
    // ---- flush: coalesced-ish output write ----
    {
        int r = tid >> 3, oi2 = tid & 7;
        int p = p0 + r;
        if (oi2 < nO && p < TOTAL)
            out[(size_t)p * CC + o0 + oi2] = outbuf[r][oi2] + bbil[o0 + oi2];
    }
#undef PREFETCH
#undef WRITE_B
#undef COMPUTE
}

extern "C" void kernel_launch(void* const* d_in, const int* in_sizes, int n_in,
                              void* d_out, int out_size, void* d_ws, size_t ws_size,
                              hipStream_t stream) {
    const float* seq   = (const float*)d_in[0];
    const float* att   = (const float*)d_in[1];
    const int*   midx  = (const int*)d_in[2];
    const int*   mmask = (const int*)d_in[3];
    const int*   hts   = (const int*)d_in[4];
    const float* Wlin  = (const float*)d_in[5];
    const float* blin  = (const float*)d_in[6];
    const float* Wseg  = (const float*)d_in[7];
    const float* bseg  = (const float*)d_in[8];
    const float* Whead = (const float*)d_in[9];
    const float* bhead = (const float*)d_in[10];
    const float* Wtail = (const float*)d_in[11];
    const float* btail = (const float*)d_in[12];
    const float* Wbil  = (const float*)d_in[13];
    const float* bbil  = (const float*)d_in[14];
    float* out = (float*)d_out;

    float* ws = (float*)d_ws;
    float* ent_emb = ws;                               // B*NE*D
    float* ea      = ent_emb + BB * NEz * DD;          // B*NE*H*L
    float* seqW    = ea + (size_t)BB * NEz * HH * LL;  // B*L*3
    float* am      = seqW + BB * LL * 3;               // B*PAIRS*F2
    float* EWh     = am + (size_t)BB * PAIRS * FF;     // B*NE*F2
    float* EWt     = EWh + BB * NEz * FF;              // B*NE*F2
    __hip_bfloat16* Wt_swz = (__hip_bfloat16*)(EWt + BB * NEz * FF);  // C*F2*F2
    __hip_bfloat16* HS_swz = Wt_swz + (size_t)CC * FF * FF;           // 54*64*256
    __hip_bfloat16* TSb    = HS_swz + (size_t)PT64 * 64 * FF;         // TOTAL*F2

    k_seqw<<<BB * LL, 64, 0, stream>>>(seq, Wlin, seqW);
    k_ent_emb<<<BB * NEz, 256, 0, stream>>>(seq, midx, mmask, ent_emb);
    k_ent_att<<<BB * NEz * HH, 256, 0, stream>>>(att, midx, mmask, ea);
    k_pair<<<BB * PAIRS, 256, 0, stream>>>(ea, seqW, Wseg, bseg, blin, am);
    k_ew<<<BB * NEz, 256, 0, stream>>>(ent_emb, Whead, bhead, Wtail, btail, EWh, EWt);
    k_wt<<<dim3(16, CC), 256, 0, stream>>>(Wbil, Wt_swz);
    k_prep<<<PT64, 256, 0, stream>>>(EWh, EWt, am, hts, HS_swz, TSb);
    k_bil_mfma<<<NWG, 512, 0, stream>>>(HS_swz, TSb, Wt_swz, bbil, out);
}